// Round 1
// baseline (316.420 us; speedup 1.0000x reference)
//
#include <hip/hip_runtime.h>
#include <hip/hip_bf16.h>

// GraphAttention: N=4096 nodes, F=1024 in-features, H=8 heads, U=128 units.
// Strategy: exact sparsification. Non-edge logits are -1e10 + O(1); after
// row-max subtraction expf underflows to exactly 0.0f in fp32, so softmax
// over edges only is exact. Build CSR once, then sparse softmax-aggregate.

constexpr int NN = 4096;
constexpr int FF = 1024;
constexpr int HH = 8;
constexpr int UU = 128;
constexpr int CC = HH * UU;      // 1024 concat channels
constexpr int MAXDEG = 128;      // mean deg ~42, +13 sigma safety
constexpr float ALPHA = 0.2f;

// ---------------------------------------------------------------- K1: CSR
__global__ __launch_bounds__(256) void build_csr(const float* __restrict__ A,
                                                 int* __restrict__ deg,
                                                 int* __restrict__ idx) {
  const int i = blockIdx.x;
  const int tid = threadIdx.x;
  __shared__ int cnt;
  if (tid == 0) cnt = 0;
  __syncthreads();
  const float4* row = reinterpret_cast<const float4*>(A + (size_t)i * NN);
  for (int c = tid; c < NN / 4; c += 256) {
    float4 v = row[c];
    if (v.x > 0.5f) { int p = atomicAdd(&cnt, 1); if (p < MAXDEG) idx[i * MAXDEG + p] = c * 4 + 0; }
    if (v.y > 0.5f) { int p = atomicAdd(&cnt, 1); if (p < MAXDEG) idx[i * MAXDEG + p] = c * 4 + 1; }
    if (v.z > 0.5f) { int p = atomicAdd(&cnt, 1); if (p < MAXDEG) idx[i * MAXDEG + p] = c * 4 + 2; }
    if (v.w > 0.5f) { int p = atomicAdd(&cnt, 1); if (p < MAXDEG) idx[i * MAXDEG + p] = c * 4 + 3; }
  }
  __syncthreads();
  if (tid == 0) deg[i] = cnt > MAXDEG ? MAXDEG : cnt;
}

// ------------------------------------------------- K2: feat = X @ W (fp32)
// feat stored [N, H*U] with channel c = h*128+u. Col-tile = one head (BN=128).
constexpr int BM = 128, BN = 128, BK = 16;

__global__ __launch_bounds__(256) void gemm_feat(const float* __restrict__ X,
                                                 const float* __restrict__ W,
                                                 float* __restrict__ feat) {
  const int bx = blockIdx.x;  // col tile == head h (8)
  const int by = blockIdx.y;  // row tile (32)
  __shared__ float As[BK][BM];  // A stored transposed: As[k][m]
  __shared__ float Bs[BK][BN];
  const int tid = threadIdx.x;
  const int tm = tid >> 4, tn = tid & 15;  // 16x16 thread grid, 8x8 microtile
  float acc[8][8] = {};
  const float* Wh = W + (size_t)bx * FF * UU;  // W[h][f][u]
  const int row0 = by * BM;

  for (int k0 = 0; k0 < FF; k0 += BK) {
#pragma unroll
    for (int q = 0; q < 2; ++q) {  // A tile: 128 rows x 16 cols, 512 float4
      int l = tid * 2 + q;
      int r = l >> 2, c4 = l & 3;
      float4 v = *reinterpret_cast<const float4*>(&X[(size_t)(row0 + r) * FF + k0 + c4 * 4]);
      As[c4 * 4 + 0][r] = v.x;
      As[c4 * 4 + 1][r] = v.y;
      As[c4 * 4 + 2][r] = v.z;
      As[c4 * 4 + 3][r] = v.w;
    }
#pragma unroll
    for (int q = 0; q < 2; ++q) {  // B tile: 16 rows x 128 cols
      int l = tid * 2 + q;
      int r = l >> 5, c4 = l & 31;
      *reinterpret_cast<float4*>(&Bs[r][c4 * 4]) =
          *reinterpret_cast<const float4*>(&Wh[(size_t)(k0 + r) * UU + c4 * 4]);
    }
    __syncthreads();
#pragma unroll
    for (int k = 0; k < BK; ++k) {
      float a[8], b[8];
#pragma unroll
      for (int i = 0; i < 8; ++i) a[i] = As[k][tm * 8 + i];
#pragma unroll
      for (int j = 0; j < 8; ++j) b[j] = Bs[k][tn * 8 + j];
#pragma unroll
      for (int i = 0; i < 8; ++i)
#pragma unroll
        for (int j = 0; j < 8; ++j) acc[i][j] += a[i] * b[j];
    }
    __syncthreads();
  }
#pragma unroll
  for (int i = 0; i < 8; ++i) {
    int n = row0 + tm * 8 + i;
#pragma unroll
    for (int j4 = 0; j4 < 2; ++j4) {
      float4 v = make_float4(acc[i][j4 * 4 + 0], acc[i][j4 * 4 + 1],
                             acc[i][j4 * 4 + 2], acc[i][j4 * 4 + 3]);
      *reinterpret_cast<float4*>(&feat[(size_t)n * CC + bx * BN + tn * 8 + j4 * 4]) = v;
    }
  }
}

// ------------------------------------- K3: s[h,n], t[h,n] = feat . a_{s,n}
__global__ __launch_bounds__(256) void st_kernel(const float* __restrict__ feat,
                                                 const float* __restrict__ a_self,
                                                 const float* __restrict__ a_neigh,
                                                 float* __restrict__ s_arr,
                                                 float* __restrict__ t_arr) {
  const int n = blockIdx.x;
  const int tid = threadIdx.x;
  const int wave = tid >> 6, lane = tid & 63;
  const float* frow = feat + (size_t)n * CC;
#pragma unroll
  for (int hh = 0; hh < 2; ++hh) {
    int h = wave * 2 + hh;
    int c0 = h * UU + lane;
    float f0 = frow[c0], f1 = frow[c0 + 64];
    float vs = f0 * a_self[c0] + f1 * a_self[c0 + 64];
    float vt = f0 * a_neigh[c0] + f1 * a_neigh[c0 + 64];
#pragma unroll
    for (int o = 32; o > 0; o >>= 1) {
      vs += __shfl_xor(vs, o);
      vt += __shfl_xor(vt, o);
    }
    if (lane == 0) {
      s_arr[h * NN + n] = vs;
      t_arr[h * NN + n] = vt;
    }
  }
}

// ------------------------- K4: sparse softmax + aggregation, one (h,i)/block
__global__ __launch_bounds__(128) void aggregate(const float* __restrict__ feat,
                                                 const float* __restrict__ s_arr,
                                                 const float* __restrict__ t_arr,
                                                 const int* __restrict__ deg_arr,
                                                 const int* __restrict__ idx_arr,
                                                 const float* __restrict__ bias,
                                                 float* __restrict__ out) {
  const int b = blockIdx.x;
  const int h = b >> 12;      // h-major: same-head blocks adjacent -> L2 locality
  const int i = b & (NN - 1);
  const int tid = threadIdx.x;  // == u in phase 2
  __shared__ float p[MAXDEG];
  __shared__ int jj[MAXDEG];
  __shared__ float wred[2][2];

  const int deg = deg_arr[i];
  const float si = s_arr[h * NN + i];
  float e = -1e30f;
  if (tid < deg) {
    int j = idx_arr[i * MAXDEG + tid];
    jj[tid] = j;
    float x = si + t_arr[h * NN + j];
    e = x > 0.0f ? x : ALPHA * x;
  }
  // block-wide max (2 waves)
  float m = e;
#pragma unroll
  for (int o = 32; o > 0; o >>= 1) m = fmaxf(m, __shfl_xor(m, o));
  if ((tid & 63) == 0) wred[0][tid >> 6] = m;
  __syncthreads();
  m = fmaxf(wred[0][0], wred[0][1]);

  float pe = (tid < deg) ? expf(e - m) : 0.0f;
  p[tid] = pe;
  float ssum = pe;
#pragma unroll
  for (int o = 32; o > 0; o >>= 1) ssum += __shfl_xor(ssum, o);
  if ((tid & 63) == 0) wred[1][tid >> 6] = ssum;
  __syncthreads();
  const float inv = 1.0f / (wred[1][0] + wred[1][1]);

  // phase 2: out[i, h*128+u] = relu(inv * sum_k p[k]*feat[jj[k], h*128+u] + b)
  const float* fh = feat + h * UU + tid;
  float acc = 0.0f;
  int k = 0;
  for (; k + 3 < deg; k += 4) {
    float p0 = p[k], p1 = p[k + 1], p2 = p[k + 2], p3 = p[k + 3];
    int j0 = jj[k], j1 = jj[k + 1], j2 = jj[k + 2], j3 = jj[k + 3];
    acc += p0 * fh[(size_t)j0 * CC] + p1 * fh[(size_t)j1 * CC] +
           p2 * fh[(size_t)j2 * CC] + p3 * fh[(size_t)j3 * CC];
  }
  for (; k < deg; ++k) acc += p[k] * fh[(size_t)jj[k] * CC];

  float o = acc * inv + bias[h * UU + tid];
  out[(size_t)i * CC + h * UU + tid] = fmaxf(o, 0.0f);
}

// ---------------------------------------------------------------- launcher
extern "C" void kernel_launch(void* const* d_in, const int* in_sizes, int n_in,
                              void* d_out, int out_size, void* d_ws, size_t ws_size,
                              hipStream_t stream) {
  const float* X       = (const float*)d_in[0];  // [1,4096,1024]
  const float* A       = (const float*)d_in[1];  // [1,4096,4096]
  const float* W       = (const float*)d_in[2];  // [8,1024,128]
  const float* a_self  = (const float*)d_in[3];  // [8,128]
  const float* a_neigh = (const float*)d_in[4];  // [8,128]
  const float* bias    = (const float*)d_in[5];  // [8,128]
  float* out = (float*)d_out;                    // [1,4096,1024]

  // workspace carve-up (~18.4 MB)
  float* feat  = (float*)d_ws;                   // 4096*1024 f32 = 16 MB
  float* s_arr = feat + (size_t)NN * CC;         // 8*4096
  float* t_arr = s_arr + HH * NN;                // 8*4096
  int*   deg   = (int*)(t_arr + HH * NN);        // 4096
  int*   idx   = deg + NN;                       // 4096*128

  hipLaunchKernelGGL(build_csr, dim3(NN), dim3(256), 0, stream, A, deg, idx);
  hipLaunchKernelGGL(gemm_feat, dim3(CC / BN, NN / BM), dim3(256), 0, stream, X, W, feat);
  hipLaunchKernelGGL(st_kernel, dim3(NN), dim3(256), 0, stream, feat, a_self, a_neigh, s_arr, t_arr);
  hipLaunchKernelGGL(aggregate, dim3(HH * NN), dim3(128), 0, stream,
                     feat, s_arr, t_arr, deg, idx, bias, out);
}

// Round 3
// 259.891 us; speedup vs baseline: 1.2175x; 1.2175x over previous
//
#include <hip/hip_runtime.h>

// GraphAttention N=4096 F=1024 H=8 U=128.
// R3 == R2 resubmit (R2 never ran: GPU acquisition timeout).
// Split-bf16 MFMA GEMM (3-term hi/lo, fp32-accurate) + exact sparse softmax.

constexpr int NN = 4096;
constexpr int FF = 1024;
constexpr int HH = 8;
constexpr int UU = 128;
constexpr int CC = HH * UU;
constexpr int MAXDEG = 128;
constexpr float ALPHA = 0.2f;

typedef __attribute__((ext_vector_type(8))) short short8;   // 8 bf16 (4 VGPRs)
typedef __attribute__((ext_vector_type(4))) float f32x4;

__device__ inline unsigned short f2bf(float x) {  // RNE float->bf16
  unsigned u = __float_as_uint(x);
  return (unsigned short)((u + 0x7fffu + ((u >> 16) & 1u)) >> 16);
}
__device__ inline float bf2f(unsigned short h) { return __uint_as_float(((unsigned)h) << 16); }

// ------------------------------------------------ K0a: X -> Xhi + Xlo (bf16)
__global__ __launch_bounds__(256) void convert_X(const float* __restrict__ X,
                                                 unsigned short* __restrict__ Xhi,
                                                 unsigned short* __restrict__ Xlo) {
  size_t base = ((size_t)blockIdx.x * 256 + threadIdx.x) * 8;
  float4 v0 = *(const float4*)(X + base);
  float4 v1 = *(const float4*)(X + base + 4);
  float xs[8] = {v0.x, v0.y, v0.z, v0.w, v1.x, v1.y, v1.z, v1.w};
  short8 vh, vl;
#pragma unroll
  for (int e = 0; e < 8; ++e) {
    unsigned short hb = f2bf(xs[e]);
    vh[e] = (short)hb;
    vl[e] = (short)f2bf(xs[e] - bf2f(hb));
  }
  *(short8*)(Xhi + base) = vh;
  *(short8*)(Xlo + base) = vl;
}

// --------------------------- K0b: W[h][f][u] -> WT[{hi,lo}][h][u][f] (bf16)
__global__ __launch_bounds__(256) void transposeW(const float* __restrict__ W,
                                                  unsigned short* __restrict__ WT) {
  const int h = blockIdx.x >> 3, ft = blockIdx.x & 7;
  const int f0 = ft * 128;
  __shared__ unsigned short hiT[128][136];  // [u][f_local], +8 pad (16B-aligned rows)
  __shared__ unsigned short loT[128][136];
  const int tid = threadIdx.x;
#pragma unroll
  for (int it = 0; it < 16; ++it) {
    int idx = it * 256 + tid;  // 0..4095 = 128 f x 32 u4
    int r = idx >> 5;
    int u4 = idx & 31;
    float4 v = *(const float4*)(W + (size_t)h * FF * UU + (size_t)(f0 + r) * UU + u4 * 4);
    float xs[4] = {v.x, v.y, v.z, v.w};
#pragma unroll
    for (int e = 0; e < 4; ++e) {
      unsigned short hb = f2bf(xs[e]);
      hiT[u4 * 4 + e][r] = hb;
      loT[u4 * 4 + e][r] = f2bf(xs[e] - bf2f(hb));
    }
  }
  __syncthreads();
#pragma unroll
  for (int it = 0; it < 8; ++it) {
    int idx = it * 256 + tid;  // 0..2047 = 128 u x 16 f8
    int u = idx >> 4, f8 = idx & 15;
    short8 vh = *(const short8*)&hiT[u][f8 * 8];
    short8 vl = *(const short8*)&loT[u][f8 * 8];
    size_t o = (size_t)h * UU * FF + (size_t)u * FF + f0 + f8 * 8;
    *(short8*)(WT + o) = vh;
    *(short8*)(WT + (size_t)HH * UU * FF + o) = vl;
  }
}

// ---------------------------------------------------------------- K1: CSR
__global__ __launch_bounds__(256) void build_csr(const float* __restrict__ A,
                                                 int* __restrict__ deg,
                                                 int* __restrict__ idx) {
  const int i = blockIdx.x;
  const int tid = threadIdx.x;
  __shared__ int cnt;
  if (tid == 0) cnt = 0;
  __syncthreads();
  const float4* row = reinterpret_cast<const float4*>(A + (size_t)i * NN);
  for (int c = tid; c < NN / 4; c += 256) {
    float4 v = row[c];
    if (v.x > 0.5f) { int p = atomicAdd(&cnt, 1); if (p < MAXDEG) idx[i * MAXDEG + p] = c * 4 + 0; }
    if (v.y > 0.5f) { int p = atomicAdd(&cnt, 1); if (p < MAXDEG) idx[i * MAXDEG + p] = c * 4 + 1; }
    if (v.z > 0.5f) { int p = atomicAdd(&cnt, 1); if (p < MAXDEG) idx[i * MAXDEG + p] = c * 4 + 2; }
    if (v.w > 0.5f) { int p = atomicAdd(&cnt, 1); if (p < MAXDEG) idx[i * MAXDEG + p] = c * 4 + 3; }
  }
  __syncthreads();
  if (tid == 0) deg[i] = cnt > MAXDEG ? MAXDEG : cnt;
}

// --------------------- K2: feat = X @ W via split-bf16 MFMA (K=3*1024)
// grid: (head, rowtile) = 8*32 = 256 blocks, 256 thr = 4 waves in 2x2,
// each wave 64x64 out via 4x4 frags of mfma_f32_16x16x32_bf16.
constexpr int NT = 48;  // 3 segments * 16 K-tiles of 64

__global__ __launch_bounds__(256) void gemm_mfma(const unsigned short* __restrict__ Xhi,
                                                 const unsigned short* __restrict__ Xlo,
                                                 const unsigned short* __restrict__ WT,
                                                 float* __restrict__ feat) {
  __shared__ char lds[2][16384];  // A tile 128x64 bf16, XOR-swizzled, double-buffered
  const int tid = threadIdx.x;
  const int w = tid >> 6, l = tid & 63;
  const int h = blockIdx.x & 7;
  const int row0 = (blockIdx.x >> 3) * 128;
  const int wr = w >> 1, wc = w & 1;

  // staging lane constants (inverse-swizzled global source, rule #21)
  const int srow = w * 32 + (l >> 3);               // + tq*8
  const int sk = ((l & 7) ^ (l >> 3)) << 3;         // k element offset
  // A-frag read constants
  const int arow = wr * 64 + (l & 15);              // + mi*16
  const int akb = (l >> 4) * 16;                    // k-byte within tile
  const int aswz = (l & 7) << 4;
  // B lane base: WT[h][col][k] with col = wc*64 + (l&15), k-offset (l>>4)*8
  const unsigned short* Bbase =
      WT + (size_t)h * UU * FF + (size_t)(wc * 64 + (l & 15)) * FF + (l >> 4) * 8;

  f32x4 acc[4][4] = {};
  short8 b0[8], b1[8];

  auto stageA = [&](int t, int buf) {
    int s = t >> 4, kt = t & 15;
    const unsigned short* src = (s == 1) ? Xlo : Xhi;
    const unsigned short* g = src + (size_t)(row0 + srow) * FF + kt * 64 + sk;
#pragma unroll
    for (int tq = 0; tq < 4; ++tq) {
      __builtin_amdgcn_global_load_lds(
          (const __attribute__((address_space(1))) unsigned int*)(g + (size_t)tq * 8 * FF),
          (__attribute__((address_space(3))) unsigned int*)(&lds[buf][w * 4096 + tq * 1024]),
          16, 0, 0);
    }
  };
  auto loadB = [&](int t, short8* b) {
    int s = t >> 4, kt = t & 15;
    const unsigned short* src = Bbase + ((s == 2) ? (size_t)HH * UU * FF : 0) + kt * 64;
#pragma unroll
    for (int ks = 0; ks < 2; ++ks)
#pragma unroll
      for (int ni = 0; ni < 4; ++ni)
        b[ks * 4 + ni] = *(const short8*)(src + (size_t)ni * 16 * FF + ks * 32);
  };
  auto compute = [&](int buf, short8* b) {
#pragma unroll
    for (int ks = 0; ks < 2; ++ks) {
      short8 a[4];
#pragma unroll
      for (int mi = 0; mi < 4; ++mi) {
        int off = (arow + mi * 16) * 128 + ((ks * 64 + akb) ^ aswz);
        a[mi] = *(const short8*)(&lds[buf][off]);
      }
#pragma unroll
      for (int mi = 0; mi < 4; ++mi)
#pragma unroll
        for (int ni = 0; ni < 4; ++ni)
          acc[mi][ni] = __builtin_amdgcn_mfma_f32_16x16x32_bf16(a[mi], b[ks * 4 + ni],
                                                                acc[mi][ni], 0, 0, 0);
    }
  };

  stageA(0, 0);
  loadB(0, b0);
  __syncthreads();
  for (int tt = 0; tt < NT; tt += 2) {
    if (tt + 1 < NT) { stageA(tt + 1, 1); loadB(tt + 1, b1); }
    compute(0, b0);
    __syncthreads();
    if (tt + 2 < NT) { stageA(tt + 2, 0); loadB(tt + 2, b0); }
    compute(1, b1);
    __syncthreads();
  }

  // epilogue: D[row=(l>>4)*4+r][col=l&15] per fragment (verified C/D layout)
  const int ccol = h * 128 + wc * 64 + (l & 15);
  const int crow0 = row0 + wr * 64 + (l >> 4) * 4;
#pragma unroll
  for (int mi = 0; mi < 4; ++mi)
#pragma unroll
    for (int ni = 0; ni < 4; ++ni)
#pragma unroll
      for (int r = 0; r < 4; ++r)
        feat[(size_t)(crow0 + mi * 16 + r) * CC + ccol + ni * 16] = acc[mi][ni][r];
}

// ------------------------------------- K3: s[h,n], t[h,n] = feat . a_{s,n}
__global__ __launch_bounds__(256) void st_kernel(const float* __restrict__ feat,
                                                 const float* __restrict__ a_self,
                                                 const float* __restrict__ a_neigh,
                                                 float* __restrict__ s_arr,
                                                 float* __restrict__ t_arr) {
  const int n = blockIdx.x;
  const int tid = threadIdx.x;
  const int wave = tid >> 6, lane = tid & 63;
  const float* frow = feat + (size_t)n * CC;
#pragma unroll
  for (int hh = 0; hh < 2; ++hh) {
    int h = wave * 2 + hh;
    int c0 = h * UU + lane;
    float f0 = frow[c0], f1 = frow[c0 + 64];
    float vs = f0 * a_self[c0] + f1 * a_self[c0 + 64];
    float vt = f0 * a_neigh[c0] + f1 * a_neigh[c0 + 64];
#pragma unroll
    for (int o = 32; o > 0; o >>= 1) {
      vs += __shfl_xor(vs, o);
      vt += __shfl_xor(vt, o);
    }
    if (lane == 0) {
      s_arr[h * NN + n] = vs;
      t_arr[h * NN + n] = vt;
    }
  }
}

// ------------------------- K4: sparse softmax + aggregation, one (h,i)/block
__global__ __launch_bounds__(128) void aggregate(const float* __restrict__ feat,
                                                 const float* __restrict__ s_arr,
                                                 const float* __restrict__ t_arr,
                                                 const int* __restrict__ deg_arr,
                                                 const int* __restrict__ idx_arr,
                                                 const float* __restrict__ bias,
                                                 float* __restrict__ out) {
  const int b = blockIdx.x;
  const int h = b >> 12;
  const int i = b & (NN - 1);
  const int tid = threadIdx.x;
  __shared__ float p[MAXDEG];
  __shared__ int jj[MAXDEG];
  __shared__ float wred[2][2];

  const int deg = deg_arr[i];
  const float si = s_arr[h * NN + i];
  float e = -1e30f;
  if (tid < deg) {
    int j = idx_arr[i * MAXDEG + tid];
    jj[tid] = j;
    float x = si + t_arr[h * NN + j];
    e = x > 0.0f ? x : ALPHA * x;
  }
  float m = e;
#pragma unroll
  for (int o = 32; o > 0; o >>= 1) m = fmaxf(m, __shfl_xor(m, o));
  if ((tid & 63) == 0) wred[0][tid >> 6] = m;
  __syncthreads();
  m = fmaxf(wred[0][0], wred[0][1]);

  float pe = (tid < deg) ? expf(e - m) : 0.0f;
  p[tid] = pe;
  float ssum = pe;
#pragma unroll
  for (int o = 32; o > 0; o >>= 1) ssum += __shfl_xor(ssum, o);
  if ((tid & 63) == 0) wred[1][tid >> 6] = ssum;
  __syncthreads();
  const float inv = 1.0f / (wred[1][0] + wred[1][1]);

  const float* fh = feat + h * UU + tid;
  float acc = 0.0f;
  int k = 0;
  for (; k + 3 < deg; k += 4) {
    float p0 = p[k], p1 = p[k + 1], p2 = p[k + 2], p3 = p[k + 3];
    int j0 = jj[k], j1 = jj[k + 1], j2 = jj[k + 2], j3 = jj[k + 3];
    acc += p0 * fh[(size_t)j0 * CC] + p1 * fh[(size_t)j1 * CC] +
           p2 * fh[(size_t)j2 * CC] + p3 * fh[(size_t)j3 * CC];
  }
  for (; k < deg; ++k) acc += p[k] * fh[(size_t)jj[k] * CC];

  float o = acc * inv + bias[h * UU + tid];
  out[(size_t)i * CC + h * UU + tid] = fmaxf(o, 0.0f);
}

// ---------------------------------------------------------------- launcher
extern "C" void kernel_launch(void* const* d_in, const int* in_sizes, int n_in,
                              void* d_out, int out_size, void* d_ws, size_t ws_size,
                              hipStream_t stream) {
  const float* X       = (const float*)d_in[0];
  const float* A       = (const float*)d_in[1];
  const float* W       = (const float*)d_in[2];
  const float* a_self  = (const float*)d_in[3];
  const float* a_neigh = (const float*)d_in[4];
  const float* bias    = (const float*)d_in[5];
  float* out = (float*)d_out;

  // workspace carve-up (~38.2 MB)
  float* feat = (float*)d_ws;                              // 16 MB
  unsigned short* Xhi = (unsigned short*)(feat + (size_t)NN * CC);  // 8 MB
  unsigned short* Xlo = Xhi + (size_t)NN * FF;             // 8 MB
  unsigned short* WT  = Xlo + (size_t)NN * FF;             // 4 MB (hi+lo panels)
  float* s_arr = (float*)(WT + (size_t)2 * HH * UU * FF);
  float* t_arr = s_arr + HH * NN;
  int* deg = (int*)(t_arr + HH * NN);
  int* idx = deg + NN;

  hipLaunchKernelGGL(convert_X, dim3(NN * FF / (256 * 8)), dim3(256), 0, stream, X, Xhi, Xlo);
  hipLaunchKernelGGL(transposeW, dim3(64), dim3(256), 0, stream, W, WT);
  hipLaunchKernelGGL(build_csr, dim3(NN), dim3(256), 0, stream, A, deg, idx);
  hipLaunchKernelGGL(gemm_mfma, dim3(256), dim3(256), 0, stream, Xhi, Xlo, WT, feat);
  hipLaunchKernelGGL(st_kernel, dim3(NN), dim3(256), 0, stream, feat, a_self, a_neigh, s_arr, t_arr);
  hipLaunchKernelGGL(aggregate, dim3(HH * NN), dim3(128), 0, stream,
                     feat, s_arr, t_arr, deg, idx, bias, out);
}

// Round 6
// 223.768 us; speedup vs baseline: 1.4141x; 1.1614x over previous
//
#include <hip/hip_runtime.h>

// GraphAttention N=4096 F=1024 H=8 U=128.
// R6 == R4 resubmit #2 (R4: broker capacity timeout; R5: container failed —
// both infra, no compile/test evidence against this source).
// gemm: 8 waves/block, A+B staged via global_load_lds w/ XOR swizzle.
// build_csr: ballot compaction. Sparse softmax path (exact) unchanged.

constexpr int NN = 4096;
constexpr int FF = 1024;
constexpr int HH = 8;
constexpr int UU = 128;
constexpr int CC = HH * UU;
constexpr int MAXDEG = 128;
constexpr float ALPHA = 0.2f;

typedef __attribute__((ext_vector_type(8))) short short8;   // 8 bf16 (4 VGPRs)
typedef __attribute__((ext_vector_type(4))) float f32x4;

__device__ inline unsigned short f2bf(float x) {  // RNE float->bf16
  unsigned u = __float_as_uint(x);
  return (unsigned short)((u + 0x7fffu + ((u >> 16) & 1u)) >> 16);
}
__device__ inline float bf2f(unsigned short h) { return __uint_as_float(((unsigned)h) << 16); }

// ------------------------------------------------ K0a: X -> Xhi + Xlo (bf16)
__global__ __launch_bounds__(256) void convert_X(const float* __restrict__ X,
                                                 unsigned short* __restrict__ Xhi,
                                                 unsigned short* __restrict__ Xlo) {
  size_t base = ((size_t)blockIdx.x * 256 + threadIdx.x) * 8;
  float4 v0 = *(const float4*)(X + base);
  float4 v1 = *(const float4*)(X + base + 4);
  float xs[8] = {v0.x, v0.y, v0.z, v0.w, v1.x, v1.y, v1.z, v1.w};
  short8 vh, vl;
#pragma unroll
  for (int e = 0; e < 8; ++e) {
    unsigned short hb = f2bf(xs[e]);
    vh[e] = (short)hb;
    vl[e] = (short)f2bf(xs[e] - bf2f(hb));
  }
  *(short8*)(Xhi + base) = vh;
  *(short8*)(Xlo + base) = vl;
}

// --------------------------- K0b: W[h][f][u] -> WT[{hi,lo}][h][u][f] (bf16)
__global__ __launch_bounds__(256) void transposeW(const float* __restrict__ W,
                                                  unsigned short* __restrict__ WT) {
  const int h = blockIdx.x >> 3, ft = blockIdx.x & 7;
  const int f0 = ft * 128;
  __shared__ unsigned short hiT[128][136];  // [u][f_local], +8 pad
  __shared__ unsigned short loT[128][136];
  const int tid = threadIdx.x;
#pragma unroll
  for (int it = 0; it < 16; ++it) {
    int idx = it * 256 + tid;  // 128 f x 32 u4
    int r = idx >> 5;
    int u4 = idx & 31;
    float4 v = *(const float4*)(W + (size_t)h * FF * UU + (size_t)(f0 + r) * UU + u4 * 4);
    float xs[4] = {v.x, v.y, v.z, v.w};
#pragma unroll
    for (int e = 0; e < 4; ++e) {
      unsigned short hb = f2bf(xs[e]);
      hiT[u4 * 4 + e][r] = hb;
      loT[u4 * 4 + e][r] = f2bf(xs[e] - bf2f(hb));
    }
  }
  __syncthreads();
#pragma unroll
  for (int it = 0; it < 8; ++it) {
    int idx = it * 256 + tid;  // 128 u x 16 f8
    int u = idx >> 4, f8 = idx & 15;
    short8 vh = *(const short8*)&hiT[u][f8 * 8];
    short8 vl = *(const short8*)&loT[u][f8 * 8];
    size_t o = (size_t)h * UU * FF + (size_t)u * FF + f0 + f8 * 8;
    *(short8*)(WT + o) = vh;
    *(short8*)(WT + (size_t)HH * UU * FF + o) = vl;
  }
}

// ------------------------------------------ K1: CSR via ballot compaction
__global__ __launch_bounds__(256) void build_csr(const float* __restrict__ A,
                                                 int* __restrict__ deg,
                                                 int* __restrict__ idx) {
  const int i = blockIdx.x;
  const int tid = threadIdx.x;
  const int lane = tid & 63;
  __shared__ int cnt;
  if (tid == 0) cnt = 0;
  __syncthreads();
  const float4* row = reinterpret_cast<const float4*>(A + (size_t)i * NN);
  for (int c = tid; c < NN / 4; c += 256) {
    float4 v = row[c];
    unsigned long long m0 = __ballot(v.x > 0.5f);
    unsigned long long m1 = __ballot(v.y > 0.5f);
    unsigned long long m2 = __ballot(v.z > 0.5f);
    unsigned long long m3 = __ballot(v.w > 0.5f);
    int wtot = __popcll(m0) + __popcll(m1) + __popcll(m2) + __popcll(m3);
    if (wtot) {
      int base = 0;
      if (lane == 0) base = atomicAdd(&cnt, wtot);
      base = __shfl(base, 0);
      unsigned long long lt = (1ull << lane) - 1;
      int c0 = __popcll(m0), c1 = __popcll(m1), c2 = __popcll(m2);
      int o;
      o = base + __popcll(m0 & lt);
      if (v.x > 0.5f && o < MAXDEG) idx[i * MAXDEG + o] = c * 4 + 0;
      o = base + c0 + __popcll(m1 & lt);
      if (v.y > 0.5f && o < MAXDEG) idx[i * MAXDEG + o] = c * 4 + 1;
      o = base + c0 + c1 + __popcll(m2 & lt);
      if (v.z > 0.5f && o < MAXDEG) idx[i * MAXDEG + o] = c * 4 + 2;
      o = base + c0 + c1 + c2 + __popcll(m3 & lt);
      if (v.w > 0.5f && o < MAXDEG) idx[i * MAXDEG + o] = c * 4 + 3;
    }
  }
  __syncthreads();
  if (tid == 0) deg[i] = cnt > MAXDEG ? MAXDEG : cnt;
}

// --------------------- K2: feat = X @ W via split-bf16 MFMA (K=3*1024)
// 256 blocks (32 rowtiles x 8 heads), 512 thr = 8 waves (2x4 wave grid),
// wave tile 64x32, A+B both staged via global_load_lds with XOR swizzle.
constexpr int NTILE = 48;  // 3 segments * 16 K-tiles of 64

__global__ __launch_bounds__(512) void gemm_mfma(const unsigned short* __restrict__ Xhi,
                                                 const unsigned short* __restrict__ Xlo,
                                                 const unsigned short* __restrict__ WT,
                                                 float* __restrict__ feat) {
  __shared__ char lds[2][32768];  // [buf][ A 16K | B 16K ]
  const int tid = threadIdx.x;
  const int w = tid >> 6, l = tid & 63;
  const int h = blockIdx.x & 7;
  const int row0 = (blockIdx.x >> 3) * 128;
  const int wr = w >> 2, wc = w & 3;

  const int lr = l >> 3;                 // staged LDS row within 8-row group
  const int sk = ((l & 7) ^ lr) * 8;     // inverse-swizzled source k-elem
  const unsigned short* WTh = WT + (size_t)h * UU * FF;

  f32x4 acc[4][2] = {};

  auto stage = [&](int t, int buf) {
    int s = t >> 4, kt = t & 15;
    const unsigned short* As = ((s == 1) ? Xlo : Xhi) +
        (size_t)(row0 + w * 16 + lr) * FF + kt * 64 + sk;
    const unsigned short* Bs = WTh + ((s == 2) ? (size_t)HH * UU * FF : (size_t)0) +
        (size_t)(w * 16 + lr) * FF + kt * 64 + sk;
    char* la = &lds[buf][w * 2048];
    char* lb = &lds[buf][16384 + w * 2048];
#pragma unroll
    for (int dr = 0; dr < 2; ++dr) {
      __builtin_amdgcn_global_load_lds(
          (const __attribute__((address_space(1))) unsigned int*)(As + (size_t)dr * 8 * FF),
          (__attribute__((address_space(3))) unsigned int*)(la + dr * 1024), 16, 0, 0);
      __builtin_amdgcn_global_load_lds(
          (const __attribute__((address_space(1))) unsigned int*)(Bs + (size_t)dr * 8 * FF),
          (__attribute__((address_space(3))) unsigned int*)(lb + dr * 1024), 16, 0, 0);
    }
  };

  const int arow = wr * 64 + (l & 15);
  const int bcol = wc * 32 + (l & 15);
  const int kswz = (l & 7) << 4;
  const int kb = (l >> 4) * 16;

  auto compute = [&](int buf) {
#pragma unroll
    for (int ks = 0; ks < 2; ++ks) {
      const int ko = ks * 64 + kb;
      short8 a[4], b[2];
#pragma unroll
      for (int mi = 0; mi < 4; ++mi)
        a[mi] = *(const short8*)(&lds[buf][(arow + mi * 16) * 128 + (ko ^ kswz)]);
#pragma unroll
      for (int ni = 0; ni < 2; ++ni)
        b[ni] = *(const short8*)(&lds[buf][16384 + (bcol + ni * 16) * 128 + (ko ^ kswz)]);
#pragma unroll
      for (int mi = 0; mi < 4; ++mi)
#pragma unroll
        for (int ni = 0; ni < 2; ++ni)
          acc[mi][ni] = __builtin_amdgcn_mfma_f32_16x16x32_bf16(a[mi], b[ni],
                                                                acc[mi][ni], 0, 0, 0);
    }
  };

  stage(0, 0);
  __syncthreads();
  for (int tt = 0; tt < NTILE; ++tt) {
    if (tt + 1 < NTILE) stage(tt + 1, (tt + 1) & 1);
    compute(tt & 1);
    __syncthreads();
  }

  // epilogue: D[row=(l>>4)*4+r][col=l&15] (verified layout)
  const int ccol = h * 128 + wc * 32 + (l & 15);
  const int crow0 = row0 + wr * 64 + (l >> 4) * 4;
#pragma unroll
  for (int mi = 0; mi < 4; ++mi)
#pragma unroll
    for (int ni = 0; ni < 2; ++ni)
#pragma unroll
      for (int r = 0; r < 4; ++r)
        feat[(size_t)(crow0 + mi * 16 + r) * CC + ccol + ni * 16] = acc[mi][ni][r];
}

// ------------------------------------- K3: s[h,n], t[h,n] = feat . a_{s,n}
__global__ __launch_bounds__(256) void st_kernel(const float* __restrict__ feat,
                                                 const float* __restrict__ a_self,
                                                 const float* __restrict__ a_neigh,
                                                 float* __restrict__ s_arr,
                                                 float* __restrict__ t_arr) {
  const int n = blockIdx.x;
  const int tid = threadIdx.x;
  const int wave = tid >> 6, lane = tid & 63;
  const float* frow = feat + (size_t)n * CC;
#pragma unroll
  for (int hh = 0; hh < 2; ++hh) {
    int h = wave * 2 + hh;
    int c0 = h * UU + lane;
    float f0 = frow[c0], f1 = frow[c0 + 64];
    float vs = f0 * a_self[c0] + f1 * a_self[c0 + 64];
    float vt = f0 * a_neigh[c0] + f1 * a_neigh[c0 + 64];
#pragma unroll
    for (int o = 32; o > 0; o >>= 1) {
      vs += __shfl_xor(vs, o);
      vt += __shfl_xor(vt, o);
    }
    if (lane == 0) {
      s_arr[h * NN + n] = vs;
      t_arr[h * NN + n] = vt;
    }
  }
}

// ------------------------- K4: sparse softmax + aggregation, one (h,i)/block
__global__ __launch_bounds__(128) void aggregate(const float* __restrict__ feat,
                                                 const float* __restrict__ s_arr,
                                                 const float* __restrict__ t_arr,
                                                 const int* __restrict__ deg_arr,
                                                 const int* __restrict__ idx_arr,
                                                 const float* __restrict__ bias,
                                                 float* __restrict__ out) {
  const int b = blockIdx.x;
  const int h = b >> 12;  // h-major for per-XCD L2 locality on feat slices
  const int i = b & (NN - 1);
  const int tid = threadIdx.x;
  __shared__ float p[MAXDEG];
  __shared__ int jj[MAXDEG];
  __shared__ float wred[2][2];

  const int deg = deg_arr[i];
  const float si = s_arr[h * NN + i];
  float e = -1e30f;
  if (tid < deg) {
    int j = idx_arr[i * MAXDEG + tid];
    jj[tid] = j;
    float x = si + t_arr[h * NN + j];
    e = x > 0.0f ? x : ALPHA * x;
  }
  float m = e;
#pragma unroll
  for (int o = 32; o > 0; o >>= 1) m = fmaxf(m, __shfl_xor(m, o));
  if ((tid & 63) == 0) wred[0][tid >> 6] = m;
  __syncthreads();
  m = fmaxf(wred[0][0], wred[0][1]);

  float pe = (tid < deg) ? expf(e - m) : 0.0f;
  p[tid] = pe;
  float ssum = pe;
#pragma unroll
  for (int o = 32; o > 0; o >>= 1) ssum += __shfl_xor(ssum, o);
  if ((tid & 63) == 0) wred[1][tid >> 6] = ssum;
  __syncthreads();
  const float inv = 1.0f / (wred[1][0] + wred[1][1]);

  const float* fh = feat + h * UU + tid;
  float acc = 0.0f;
  int k = 0;
  for (; k + 3 < deg; k += 4) {
    float p0 = p[k], p1 = p[k + 1], p2 = p[k + 2], p3 = p[k + 3];
    int j0 = jj[k], j1 = jj[k + 1], j2 = jj[k + 2], j3 = jj[k + 3];
    acc += p0 * fh[(size_t)j0 * CC] + p1 * fh[(size_t)j1 * CC] +
           p2 * fh[(size_t)j2 * CC] + p3 * fh[(size_t)j3 * CC];
  }
  for (; k < deg; ++k) acc += p[k] * fh[(size_t)jj[k] * CC];

  float o = acc * inv + bias[h * UU + tid];
  out[(size_t)i * CC + h * UU + tid] = fmaxf(o, 0.0f);
}

// ---------------------------------------------------------------- launcher
extern "C" void kernel_launch(void* const* d_in, const int* in_sizes, int n_in,
                              void* d_out, int out_size, void* d_ws, size_t ws_size,
                              hipStream_t stream) {
  const float* X       = (const float*)d_in[0];
  const float* A       = (const float*)d_in[1];
  const float* W       = (const float*)d_in[2];
  const float* a_self  = (const float*)d_in[3];
  const float* a_neigh = (const float*)d_in[4];
  const float* bias    = (const float*)d_in[5];
  float* out = (float*)d_out;

  float* feat = (float*)d_ws;                              // 16 MB
  unsigned short* Xhi = (unsigned short*)(feat + (size_t)NN * CC);  // 8 MB
  unsigned short* Xlo = Xhi + (size_t)NN * FF;             // 8 MB
  unsigned short* WT  = Xlo + (size_t)NN * FF;             // 4 MB (hi+lo)
  float* s_arr = (float*)(WT + (size_t)2 * HH * UU * FF);
  float* t_arr = s_arr + HH * NN;
  int* deg = (int*)(t_arr + HH * NN);
  int* idx = deg + NN;

  hipLaunchKernelGGL(convert_X, dim3(NN * FF / (256 * 8)), dim3(256), 0, stream, X, Xhi, Xlo);
  hipLaunchKernelGGL(transposeW, dim3(64), dim3(256), 0, stream, W, WT);
  hipLaunchKernelGGL(build_csr, dim3(NN), dim3(256), 0, stream, A, deg, idx);
  hipLaunchKernelGGL(gemm_mfma, dim3(256), dim3(512), 0, stream, Xhi, Xlo, WT, feat);
  hipLaunchKernelGGL(st_kernel, dim3(NN), dim3(256), 0, stream, feat, a_self, a_neigh, s_arr, t_arr);
  hipLaunchKernelGGL(aggregate, dim3(HH * NN), dim3(128), 0, stream,
                     feat, s_arr, t_arr, deg, idx, bias, out);
}